// Round 1
// baseline (643.539 us; speedup 1.0000x reference)
//
#include <hip/hip_runtime.h>
#include <math.h>

#define N_NODES 50000
#define N_EDGES 800000
#define N_GRAPHS 64
#define NEG 0.2f

// ---------------- GEMM: C[M,N] = A[M,K] * B[K,N], f32 row-major ----------------
// BM=BN=64, BK=32, 256 threads, 4x4 micro-tile per thread.
__global__ __launch_bounds__(256) void gemm_tile(
    const float* __restrict__ A, const float* __restrict__ B,
    float* __restrict__ C, int M, int N, int K) {
  __shared__ float As[32][64];
  __shared__ float Bs[32][64];
  int m0 = blockIdx.x * 64, n0 = blockIdx.y * 64;
  int t = threadIdx.x;
  int tn = t & 15, tm = t >> 4;
  float acc[4][4] = {};
  for (int k0 = 0; k0 < K; k0 += 32) {
    int m_a = t >> 3, k4 = t & 7;
    #pragma unroll
    for (int half = 0; half < 2; ++half) {
      int m = m_a + half * 32;
      int row = m0 + m;
      float4 v = make_float4(0.f, 0.f, 0.f, 0.f);
      if (row < M) v = *(const float4*)&A[(size_t)row * K + k0 + k4 * 4];
      As[k4 * 4 + 0][m] = v.x; As[k4 * 4 + 1][m] = v.y;
      As[k4 * 4 + 2][m] = v.z; As[k4 * 4 + 3][m] = v.w;
    }
    int k_b = t >> 4, n4 = t & 15;
    #pragma unroll
    for (int half = 0; half < 2; ++half) {
      int k = k_b + half * 16;
      float4 v = *(const float4*)&B[(size_t)(k0 + k) * N + n0 + n4 * 4];
      *(float4*)&Bs[k][n4 * 4] = v;
    }
    __syncthreads();
    #pragma unroll
    for (int kk = 0; kk < 32; ++kk) {
      float4 a = *(const float4*)&As[kk][tm * 4];
      float4 b = *(const float4*)&Bs[kk][tn * 4];
      float av[4] = {a.x, a.y, a.z, a.w}, bv[4] = {b.x, b.y, b.z, b.w};
      #pragma unroll
      for (int i = 0; i < 4; i++)
        #pragma unroll
        for (int j = 0; j < 4; j++) acc[i][j] += av[i] * bv[j];
    }
    __syncthreads();
  }
  #pragma unroll
  for (int i = 0; i < 4; i++) {
    int row = m0 + tm * 4 + i;
    if (row < M) {
      float4 v = make_float4(acc[i][0], acc[i][1], acc[i][2], acc[i][3]);
      *(float4*)&C[(size_t)row * N + n0 + tn * 4] = v;
    }
  }
}

// ---------------- per-node attention logits, layer 1 (4 heads x 64) ----------------
__global__ __launch_bounds__(256) void logits1_kernel(
    const float* __restrict__ h1, const float* __restrict__ a_src,
    const float* __restrict__ a_dst, float* __restrict__ al_s,
    float* __restrict__ al_d) {
  int idx = blockIdx.x * 256 + threadIdx.x;  // n*4 + h
  if (idx >= N_NODES * 4) return;
  int n = idx >> 2, h = idx & 3;
  const float4* hp = (const float4*)&h1[(size_t)n * 256 + h * 64];
  const float4* sp = (const float4*)&a_src[h * 64];
  const float4* dp = (const float4*)&a_dst[h * 64];
  float ss = 0.f, sd = 0.f;
  #pragma unroll
  for (int i = 0; i < 16; i++) {
    float4 v = hp[i], s4 = sp[i], d4 = dp[i];
    ss += v.x * s4.x + v.y * s4.y + v.z * s4.z + v.w * s4.w;
    sd += v.x * d4.x + v.y * d4.y + v.z * d4.z + v.w * d4.w;
  }
  al_s[idx] = ss;
  al_d[idx] = sd;
}

// ---------------- per-node attention logits, layer 2 (1 head x 128) ----------------
__global__ __launch_bounds__(256) void logits2_kernel(
    const float* __restrict__ h2, const float* __restrict__ a_src,
    const float* __restrict__ a_dst, float* __restrict__ al_s,
    float* __restrict__ al_d) {
  int n = blockIdx.x * 256 + threadIdx.x;
  if (n >= N_NODES) return;
  const float4* hp = (const float4*)&h2[(size_t)n * 128];
  float ss = 0.f, sd = 0.f;
  #pragma unroll
  for (int i = 0; i < 32; i++) {
    float4 v = hp[i];
    float4 s4 = ((const float4*)a_src)[i];
    float4 d4 = ((const float4*)a_dst)[i];
    ss += v.x * s4.x + v.y * s4.y + v.z * s4.z + v.w * s4.w;
    sd += v.x * d4.x + v.y * d4.y + v.z * d4.z + v.w * d4.w;
  }
  al_s[n] = ss;
  al_d[n] = sd;
}

// ---------------- CSR build ----------------
__global__ __launch_bounds__(256) void count_kernel(const int* __restrict__ dst,
                                                    int* __restrict__ cnt) {
  int e = blockIdx.x * 256 + threadIdx.x;
  if (e < N_EDGES) atomicAdd(&cnt[dst[e]], 1);
}

__global__ __launch_bounds__(1024) void scan_kernel(const int* __restrict__ cnt,
                                                    int* __restrict__ row_start,
                                                    int* __restrict__ cursor) {
  __shared__ int sh[1024];
  __shared__ int carry;
  int t = threadIdx.x;
  if (t == 0) carry = 0;
  __syncthreads();
  for (int base = 0; base < N_NODES; base += 1024) {
    int i = base + t;
    int v = (i < N_NODES) ? cnt[i] : 0;
    sh[t] = v;
    __syncthreads();
    for (int off = 1; off < 1024; off <<= 1) {
      int tv = (t >= off) ? sh[t - off] : 0;
      __syncthreads();
      sh[t] += tv;
      __syncthreads();
    }
    int incl = sh[t] + carry;
    int excl = incl - v;
    if (i < N_NODES) { row_start[i] = excl; cursor[i] = excl; }
    __syncthreads();
    if (t == 1023) carry = incl;
    __syncthreads();
  }
  if (t == 0) row_start[N_NODES] = carry;
}

__global__ __launch_bounds__(256) void scatter_kernel(
    const int* __restrict__ src, const int* __restrict__ dst,
    int* __restrict__ cursor, int* __restrict__ csr_src) {
  int e = blockIdx.x * 256 + threadIdx.x;
  if (e < N_EDGES) {
    int p = atomicAdd(&cursor[dst[e]], 1);
    csr_src[p] = src[e];
  }
}

// ---------------- layer-1 aggregation: one wave per dst node ----------------
// fused: softmax (no max-sub) numerator+denominator in one CSR pass, +bias, ELU
__global__ __launch_bounds__(256) void agg1_kernel(
    const float* __restrict__ h1, const float* __restrict__ al_s,
    const float* __restrict__ al_d, const int* __restrict__ row_start,
    const int* __restrict__ csr_src, const float* __restrict__ b1,
    float* __restrict__ out) {
  int wave = (blockIdx.x * 256 + threadIdx.x) >> 6;
  int lane = threadIdx.x & 63;
  if (wave >= N_NODES) return;
  int d = wave;
  float4 ald4 = *(const float4*)&al_d[d * 4];
  float aldv[4] = {ald4.x, ald4.y, ald4.z, ald4.w};
  int head = lane >> 4;  // (lane*4)/64
  float wsum = 0.f;
  float4 acc = make_float4(0.f, 0.f, 0.f, 0.f);
  int beg = row_start[d], end = row_start[d + 1];
  for (int j = beg - 1; j < end; ++j) {   // j==beg-1 is the self-loop
    int s = (j < beg) ? d : csr_src[j];
    float4 als4 = *(const float4*)&al_s[s * 4];
    float ev[4] = {als4.x + aldv[0], als4.y + aldv[1], als4.z + aldv[2],
                   als4.w + aldv[3]};
    float w[4];
    #pragma unroll
    for (int h = 0; h < 4; h++) {
      float e = ev[h];
      e = e > 0.f ? e : NEG * e;
      w[h] = __expf(e);
    }
    wsum += w[head];
    float4 v = *(const float4*)&h1[(size_t)s * 256 + lane * 4];
    float wh = w[head];
    acc.x += wh * v.x; acc.y += wh * v.y; acc.z += wh * v.z; acc.w += wh * v.w;
  }
  float inv = 1.f / (wsum + 1e-16f);
  float4 bb = *(const float4*)&b1[lane * 4];
  float o[4] = {acc.x * inv + bb.x, acc.y * inv + bb.y, acc.z * inv + bb.z,
                acc.w * inv + bb.w};
  #pragma unroll
  for (int i = 0; i < 4; i++) o[i] = o[i] > 0.f ? o[i] : expm1f(o[i]);
  *(float4*)&out[(size_t)d * 256 + lane * 4] =
      make_float4(o[0], o[1], o[2], o[3]);
}

// ---------------- layer-2 aggregation: one wave per dst node ----------------
__global__ __launch_bounds__(256) void agg2_kernel(
    const float* __restrict__ h2, const float* __restrict__ al_s,
    const float* __restrict__ al_d, const int* __restrict__ row_start,
    const int* __restrict__ csr_src, const float* __restrict__ b2,
    float* __restrict__ out) {
  int wave = (blockIdx.x * 256 + threadIdx.x) >> 6;
  int lane = threadIdx.x & 63;
  if (wave >= N_NODES) return;
  int d = wave;
  float ald = al_d[d];
  float wsum = 0.f;
  float2 acc = make_float2(0.f, 0.f);
  int beg = row_start[d], end = row_start[d + 1];
  for (int j = beg - 1; j < end; ++j) {
    int s = (j < beg) ? d : csr_src[j];
    float e = al_s[s] + ald;
    e = e > 0.f ? e : NEG * e;
    float w = __expf(e);
    wsum += w;
    float2 v = *(const float2*)&h2[(size_t)s * 128 + lane * 2];
    acc.x += w * v.x;
    acc.y += w * v.y;
  }
  float inv = 1.f / (wsum + 1e-16f);
  float2 bb = *(const float2*)&b2[lane * 2];
  float o0 = acc.x * inv + bb.x, o1 = acc.y * inv + bb.y;
  o0 = o0 > 0.f ? o0 : expm1f(o0);
  o1 = o1 > 0.f ? o1 : expm1f(o1);
  *(float2*)&out[(size_t)d * 128 + lane * 2] = make_float2(o0, o1);
}

// ---------------- pooling: run-length partial sums (batch is sorted) ----------------
#define NPB 512
__global__ __launch_bounds__(256) void pool_kernel(const float* __restrict__ y,
                                                   const int* __restrict__ batch,
                                                   float* __restrict__ psum) {
  int c = threadIdx.x & 127, sub = threadIdx.x >> 7;
  int n0 = blockIdx.x * NPB;
  int nend = n0 + NPB; if (nend > N_NODES) nend = N_NODES;
  int curg = -1;
  float acc = 0.f;
  for (int n = n0 + sub; n < nend; n += 2) {
    int g = batch[n];
    if (g != curg) {
      if (curg >= 0) atomicAdd(&psum[curg * 128 + c], acc);
      acc = 0.f;
      curg = g;
    }
    acc += y[(size_t)n * 128 + c];
  }
  if (curg >= 0) atomicAdd(&psum[curg * 128 + c], acc);
}

__global__ __launch_bounds__(256) void gcnt_kernel(const int* __restrict__ batch,
                                                   float* __restrict__ cntg) {
  __shared__ int sh[N_GRAPHS];
  int t = threadIdx.x;
  if (t < N_GRAPHS) sh[t] = 0;
  __syncthreads();
  int n = blockIdx.x * 256 + t;
  if (n < N_NODES) atomicAdd(&sh[batch[n]], 1);
  __syncthreads();
  if (t < N_GRAPHS && sh[t]) atomicAdd(&cntg[t], (float)sh[t]);
}

// ---------------- mean + FC + ReLU: one block per graph ----------------
__global__ __launch_bounds__(128) void fc_kernel(
    const float* __restrict__ psum, const float* __restrict__ cntg,
    const float* __restrict__ fcW, const float* __restrict__ fcb,
    float* __restrict__ out) {
  __shared__ float pr[128];
  int g = blockIdx.x, c = threadIdx.x;
  float cnt = cntg[g];
  cnt = cnt > 1.f ? cnt : 1.f;
  pr[c] = psum[g * 128 + c] / cnt;
  __syncthreads();
  float s = fcb[c];
  #pragma unroll 8
  for (int k = 0; k < 128; k++) s += pr[k] * fcW[k * 128 + c];
  out[g * 128 + c] = fmaxf(s, 0.f);
}

extern "C" void kernel_launch(void* const* d_in, const int* in_sizes, int n_in,
                              void* d_out, int out_size, void* d_ws,
                              size_t ws_size, hipStream_t stream) {
  const float* x      = (const float*)d_in[0];
  const int*   ei     = (const int*)d_in[1];
  const int*   batch  = (const int*)d_in[2];
  const float* W1     = (const float*)d_in[3];
  const float* a1_src = (const float*)d_in[4];
  const float* a1_dst = (const float*)d_in[5];
  const float* b1     = (const float*)d_in[6];
  const float* W2     = (const float*)d_in[7];
  const float* a2_src = (const float*)d_in[8];
  const float* a2_dst = (const float*)d_in[9];
  const float* b2     = (const float*)d_in[10];
  const float* fc_W   = (const float*)d_in[11];
  const float* fc_b   = (const float*)d_in[12];
  float* out = (float*)d_out;

  const int* srcp = ei;
  const int* dstp = ei + N_EDGES;

  // ---- workspace layout (floats then ints) ----
  float* A    = (float*)d_ws;            // h1 [50000*256], later h2 [50000*128]
  float* Bb   = A + (size_t)N_NODES * 256;  // x2 (elu agg1) [50000*256], later y [50000*128]
  float* al1s = Bb + (size_t)N_NODES * 256;
  float* al1d = al1s + N_NODES * 4;
  float* al2s = al1d + N_NODES * 4;
  float* al2d = al2s + N_NODES;
  float* psum = al2d + N_NODES;          // [64*128]
  float* cntg = psum + N_GRAPHS * 128;   // [64]
  int* cnt    = (int*)(cntg + N_GRAPHS); // [50000]
  int* cursor = cnt + N_NODES;           // [50000]
  int* rowst  = cursor + N_NODES;        // [50001]
  int* csrc   = rowst + N_NODES + 8;     // [800000]
  size_t needed = (size_t)((char*)(csrc + N_EDGES) - (char*)d_ws);
  if (ws_size < needed) return;  // not enough scratch; bail

  hipMemsetAsync(cnt, 0, N_NODES * sizeof(int), stream);
  hipMemsetAsync(psum, 0, (N_GRAPHS * 128 + N_GRAPHS) * sizeof(float), stream);

  // CSR build (by dst)
  count_kernel<<<(N_EDGES + 255) / 256, 256, 0, stream>>>(dstp, cnt);
  scan_kernel<<<1, 1024, 0, stream>>>(cnt, rowst, cursor);
  scatter_kernel<<<(N_EDGES + 255) / 256, 256, 0, stream>>>(srcp, dstp, cursor, csrc);

  // layer 1
  gemm_tile<<<dim3((N_NODES + 63) / 64, 4), 256, 0, stream>>>(x, W1, A, N_NODES, 256, 128);
  logits1_kernel<<<(N_NODES * 4 + 255) / 256, 256, 0, stream>>>(A, a1_src, a1_dst, al1s, al1d);
  agg1_kernel<<<(N_NODES + 3) / 4, 256, 0, stream>>>(A, al1s, al1d, rowst, csrc, b1, Bb);

  // layer 2 (h2 overwrites h1 in A; y overwrites x2 in Bb)
  gemm_tile<<<dim3((N_NODES + 63) / 64, 2), 256, 0, stream>>>(Bb, W2, A, N_NODES, 128, 256);
  logits2_kernel<<<(N_NODES + 255) / 256, 256, 0, stream>>>(A, a2_src, a2_dst, al2s, al2d);
  agg2_kernel<<<(N_NODES + 3) / 4, 256, 0, stream>>>(A, al2s, al2d, rowst, csrc, b2, Bb);

  // pool + fc
  pool_kernel<<<(N_NODES + NPB - 1) / NPB, 256, 0, stream>>>(Bb, batch, psum);
  gcnt_kernel<<<(N_NODES + 255) / 256, 256, 0, stream>>>(batch, cntg);
  fc_kernel<<<N_GRAPHS, 128, 0, stream>>>(psum, cntg, fc_W, fc_b, out);
}

// Round 2
// 403.104 us; speedup vs baseline: 1.5965x; 1.5965x over previous
//
#include <hip/hip_runtime.h>
#include <math.h>

#define N_NODES 50000
#define N_EDGES 800000
#define N_GRAPHS 64
#define NEG 0.2f

typedef unsigned short us;
typedef us us2 __attribute__((ext_vector_type(2)));
typedef us us4 __attribute__((ext_vector_type(4)));
typedef us us8 __attribute__((ext_vector_type(8)));
typedef short bf16x8 __attribute__((ext_vector_type(8)));
typedef float f32x4 __attribute__((ext_vector_type(4)));

__device__ __forceinline__ us bf16rn(float f) {
  unsigned int u = __float_as_uint(f);
  u += 0x7FFFu + ((u >> 16) & 1u);
  return (us)(u >> 16);
}
__device__ __forceinline__ float bf2f(us h) {
  return __uint_as_float(((unsigned int)h) << 16);
}

// ---------------- W conversion: W[K,N] f32 -> Wt_hi/lo [N][K] bf16 ----------------
__global__ __launch_bounds__(256) void convW_kernel(const float* __restrict__ W,
                                                    us* __restrict__ outh,
                                                    us* __restrict__ outl,
                                                    int K, int N) {
  int idx = blockIdx.x * 256 + threadIdx.x;
  if (idx >= K * N) return;
  int n = idx / K, k = idx - n * K;
  float f = W[(size_t)k * N + n];
  us h = bf16rn(f);
  outh[idx] = h;
  outl[idx] = bf16rn(f - bf2f(h));
}

// ---------------- MFMA GEMM, bf16x3 split precision ----------------
// C[M,N](bf16) = A[M,K](f32) * Wt (pre-split [N][K] bf16 hi/lo)
// BM=128, BN=128, BK=32; 256 threads = 4 waves (2x2), each wave 64x64.
__global__ __launch_bounds__(256, 2) void gemm_bf16x3(
    const float* __restrict__ A, const us* __restrict__ Bth,
    const us* __restrict__ Btl, us* __restrict__ C, int M, int N, int K) {
  __shared__ us Ah[128][40];
  __shared__ us Al[128][40];
  __shared__ us Bh[128][40];
  __shared__ us Bl[128][40];
  int t = threadIdx.x;
  int m0 = blockIdx.x * 128;
  int n0 = blockIdx.y * 128;
  int w = t >> 6, l = t & 63;
  int wr = w >> 1, wc = w & 1;
  int l15 = l & 15, g = l >> 4;

  f32x4 acc[4][4] = {};

  for (int kb = 0; kb < K; kb += 32) {
    // stage A: 128 rows x 32 k (f32) -> split hi/lo
    #pragma unroll
    for (int i = 0; i < 4; i++) {
      int slot = i * 256 + t;
      int row = slot >> 3, kq = slot & 7;
      float4 v = make_float4(0.f, 0.f, 0.f, 0.f);
      if (m0 + row < M) v = *(const float4*)&A[(size_t)(m0 + row) * K + kb + kq * 4];
      us h0 = bf16rn(v.x), h1 = bf16rn(v.y), h2 = bf16rn(v.z), h3 = bf16rn(v.w);
      us4 hv = {h0, h1, h2, h3};
      us4 lv = {bf16rn(v.x - bf2f(h0)), bf16rn(v.y - bf2f(h1)),
                bf16rn(v.z - bf2f(h2)), bf16rn(v.w - bf2f(h3))};
      *(us4*)&Ah[row][kq * 4] = hv;
      *(us4*)&Al[row][kq * 4] = lv;
    }
    // stage B: Wt rows n0..n0+127, k slab [kb, kb+32)
    #pragma unroll
    for (int i = 0; i < 2; i++) {
      int slot = i * 256 + t;
      int n = slot >> 2, kq = slot & 3;
      size_t gidx = (size_t)(n0 + n) * K + kb + kq * 8;
      *(us8*)&Bh[n][kq * 8] = *(const us8*)&Bth[gidx];
      *(us8*)&Bl[n][kq * 8] = *(const us8*)&Btl[gidx];
    }
    __syncthreads();

    bf16x8 af[4], al4[4], bf[4], bl4[4];
    #pragma unroll
    for (int i = 0; i < 4; i++) {
      af[i]  = *(const bf16x8*)&Ah[wr * 64 + i * 16 + l15][g * 8];
      al4[i] = *(const bf16x8*)&Al[wr * 64 + i * 16 + l15][g * 8];
      bf[i]  = *(const bf16x8*)&Bh[wc * 64 + i * 16 + l15][g * 8];
      bl4[i] = *(const bf16x8*)&Bl[wc * 64 + i * 16 + l15][g * 8];
    }
    #pragma unroll
    for (int i = 0; i < 4; i++)
      #pragma unroll
      for (int j = 0; j < 4; j++) {
        acc[i][j] = __builtin_amdgcn_mfma_f32_16x16x32_bf16(af[i], bf[j], acc[i][j], 0, 0, 0);
        acc[i][j] = __builtin_amdgcn_mfma_f32_16x16x32_bf16(af[i], bl4[j], acc[i][j], 0, 0, 0);
        acc[i][j] = __builtin_amdgcn_mfma_f32_16x16x32_bf16(al4[i], bf[j], acc[i][j], 0, 0, 0);
      }
    __syncthreads();
  }

  // C write: frag (i,j), reg r -> row = wr*64+i*16+g*4+r, col = wc*64+j*16+l15
  #pragma unroll
  for (int i = 0; i < 4; i++)
    #pragma unroll
    for (int j = 0; j < 4; j++)
      #pragma unroll
      for (int r = 0; r < 4; r++) {
        int row = m0 + wr * 64 + i * 16 + g * 4 + r;
        if (row < M) {
          int col = n0 + wc * 64 + j * 16 + l15;
          C[(size_t)row * N + col] = bf16rn(acc[i][j][r]);
        }
      }
}

// ---------------- logits layer 1: h1b bf16 [N,256] -> al_s/al_d [N,4] ----------------
__global__ __launch_bounds__(256) void logits1_kernel(
    const us* __restrict__ h1b, const float* __restrict__ a_src,
    const float* __restrict__ a_dst, float* __restrict__ al_s,
    float* __restrict__ al_d) {
  int idx = blockIdx.x * 256 + threadIdx.x;  // n*4 + h
  if (idx >= N_NODES * 4) return;
  int n = idx >> 2, h = idx & 3;
  const us* hp = &h1b[(size_t)n * 256 + h * 64];
  float ss = 0.f, sd = 0.f;
  #pragma unroll
  for (int i = 0; i < 8; i++) {
    us8 v = *(const us8*)&hp[i * 8];
    #pragma unroll
    for (int j = 0; j < 8; j++) {
      float f = bf2f(v[j]);
      ss += f * a_src[h * 64 + i * 8 + j];
      sd += f * a_dst[h * 64 + i * 8 + j];
    }
  }
  al_s[idx] = ss;
  al_d[idx] = sd;
}

// ---------------- logits layer 2: h2b bf16 [N,128] -> al_s/al_d [N] ----------------
__global__ __launch_bounds__(256) void logits2_kernel(
    const us* __restrict__ h2b, const float* __restrict__ a_src,
    const float* __restrict__ a_dst, float* __restrict__ al_s,
    float* __restrict__ al_d) {
  int n = blockIdx.x * 256 + threadIdx.x;
  if (n >= N_NODES) return;
  const us* hp = &h2b[(size_t)n * 128];
  float ss = 0.f, sd = 0.f;
  #pragma unroll
  for (int i = 0; i < 16; i++) {
    us8 v = *(const us8*)&hp[i * 8];
    #pragma unroll
    for (int j = 0; j < 8; j++) {
      float f = bf2f(v[j]);
      ss += f * a_src[i * 8 + j];
      sd += f * a_dst[i * 8 + j];
    }
  }
  al_s[n] = ss;
  al_d[n] = sd;
}

// ---------------- CSR build ----------------
__global__ __launch_bounds__(256) void count_kernel(const int* __restrict__ dst,
                                                    int* __restrict__ cnt) {
  int e = blockIdx.x * 256 + threadIdx.x;
  if (e < N_EDGES) atomicAdd(&cnt[dst[e]], 1);
}

// per-block inclusive scan (256 elems) via shfl; writes incl to itmp, total to bsum
__global__ __launch_bounds__(256) void scan1_kernel(const int* __restrict__ cnt,
                                                    int* __restrict__ itmp,
                                                    int* __restrict__ bsum) {
  int i = blockIdx.x * 256 + threadIdx.x;
  int v = (i < N_NODES) ? cnt[i] : 0;
  int lane = threadIdx.x & 63, w = threadIdx.x >> 6;
  int s = v;
  #pragma unroll
  for (int off = 1; off < 64; off <<= 1) {
    int tv = __shfl_up(s, off);
    if (lane >= off) s += tv;
  }
  __shared__ int wsum[4];
  if (lane == 63) wsum[w] = s;
  __syncthreads();
  int add = 0;
  for (int p = 0; p < w; p++) add += wsum[p];
  s += add;
  if (i < N_NODES) itmp[i] = s;
  if (threadIdx.x == 255) bsum[blockIdx.x] = s;
}

// scan of 196 block sums -> exclusive boff
__global__ __launch_bounds__(256) void scan2_kernel(const int* __restrict__ bsum,
                                                    int* __restrict__ boff,
                                                    int nb) {
  int t = threadIdx.x;
  int v = (t < nb) ? bsum[t] : 0;
  int lane = t & 63, w = t >> 6;
  int s = v;
  #pragma unroll
  for (int off = 1; off < 64; off <<= 1) {
    int tv = __shfl_up(s, off);
    if (lane >= off) s += tv;
  }
  __shared__ int wsum[4];
  if (lane == 63) wsum[w] = s;
  __syncthreads();
  int add = 0;
  for (int p = 0; p < w; p++) add += wsum[p];
  s += add;
  if (t < nb) boff[t] = s - v;
}

__global__ __launch_bounds__(256) void scan3_kernel(const int* __restrict__ cnt,
                                                    const int* __restrict__ itmp,
                                                    const int* __restrict__ boff,
                                                    int* __restrict__ rowst,
                                                    int* __restrict__ cursor) {
  int i = blockIdx.x * 256 + threadIdx.x;
  if (i < N_NODES) {
    int excl = itmp[i] - cnt[i] + boff[i >> 8];
    rowst[i] = excl;
    cursor[i] = excl;
  }
  if (i == 0) rowst[N_NODES] = N_EDGES;
}

__global__ __launch_bounds__(256) void scatter_kernel(
    const int* __restrict__ src, const int* __restrict__ dst,
    int* __restrict__ cursor, int* __restrict__ csr_src) {
  int e = blockIdx.x * 256 + threadIdx.x;
  if (e < N_EDGES) {
    int p = atomicAdd(&cursor[dst[e]], 1);
    csr_src[p] = src[e];
  }
}

// ---------------- layer-1 aggregation ----------------
__device__ __forceinline__ void agg1_edge(int s, int head, int lane, float ald,
                                          const float* __restrict__ al_s,
                                          const us* __restrict__ h1b,
                                          float& wsum, float4& acc) {
  float al = al_s[s * 4 + head];
  us4 hv = *(const us4*)&h1b[(size_t)s * 256 + lane * 4];
  float e = al + ald;
  e = e > 0.f ? e : NEG * e;
  float wgt = __expf(e);
  wsum += wgt;
  acc.x += wgt * bf2f(hv[0]);
  acc.y += wgt * bf2f(hv[1]);
  acc.z += wgt * bf2f(hv[2]);
  acc.w += wgt * bf2f(hv[3]);
}

__global__ __launch_bounds__(256) void agg1_kernel(
    const us* __restrict__ h1b, const float* __restrict__ al_s,
    const float* __restrict__ al_d, const int* __restrict__ rowst,
    const int* __restrict__ csrc, const float* __restrict__ b1,
    float* __restrict__ out) {
  int d = (blockIdx.x * 256 + threadIdx.x) >> 6;
  int lane = threadIdx.x & 63;
  if (d >= N_NODES) return;
  int head = lane >> 4;
  float ald = al_d[d * 4 + head];
  float wsum = 0.f;
  float4 acc = make_float4(0.f, 0.f, 0.f, 0.f);
  int beg = rowst[d], end = rowst[d + 1];
  agg1_edge(d, head, lane, ald, al_s, h1b, wsum, acc);  // self-loop
  int j = beg;
  for (; j + 1 < end; j += 2) {
    int s0 = csrc[j], s1 = csrc[j + 1];
    agg1_edge(s0, head, lane, ald, al_s, h1b, wsum, acc);
    agg1_edge(s1, head, lane, ald, al_s, h1b, wsum, acc);
  }
  if (j < end) agg1_edge(csrc[j], head, lane, ald, al_s, h1b, wsum, acc);
  float inv = 1.f / (wsum + 1e-16f);
  float4 bb = *(const float4*)&b1[lane * 4];
  float o[4] = {acc.x * inv + bb.x, acc.y * inv + bb.y, acc.z * inv + bb.z,
                acc.w * inv + bb.w};
  #pragma unroll
  for (int i = 0; i < 4; i++) o[i] = o[i] > 0.f ? o[i] : expm1f(o[i]);
  *(float4*)&out[(size_t)d * 256 + lane * 4] = make_float4(o[0], o[1], o[2], o[3]);
}

// ---------------- layer-2 aggregation ----------------
__device__ __forceinline__ void agg2_edge(int s, int lane, float ald,
                                          const float* __restrict__ al_s,
                                          const us* __restrict__ h2b,
                                          float& wsum, float& a0, float& a1) {
  float e = al_s[s] + ald;
  e = e > 0.f ? e : NEG * e;
  float wgt = __expf(e);
  wsum += wgt;
  us2 hv = *(const us2*)&h2b[(size_t)s * 128 + lane * 2];
  a0 += wgt * bf2f(hv[0]);
  a1 += wgt * bf2f(hv[1]);
}

__global__ __launch_bounds__(256) void agg2_kernel(
    const us* __restrict__ h2b, const float* __restrict__ al_s,
    const float* __restrict__ al_d, const int* __restrict__ rowst,
    const int* __restrict__ csrc, const float* __restrict__ b2,
    float* __restrict__ out) {
  int d = (blockIdx.x * 256 + threadIdx.x) >> 6;
  int lane = threadIdx.x & 63;
  if (d >= N_NODES) return;
  float ald = al_d[d];
  float wsum = 0.f, a0 = 0.f, a1 = 0.f;
  int beg = rowst[d], end = rowst[d + 1];
  agg2_edge(d, lane, ald, al_s, h2b, wsum, a0, a1);  // self-loop
  int j = beg;
  for (; j + 1 < end; j += 2) {
    int s0 = csrc[j], s1 = csrc[j + 1];
    agg2_edge(s0, lane, ald, al_s, h2b, wsum, a0, a1);
    agg2_edge(s1, lane, ald, al_s, h2b, wsum, a0, a1);
  }
  if (j < end) agg2_edge(csrc[j], lane, ald, al_s, h2b, wsum, a0, a1);
  float inv = 1.f / (wsum + 1e-16f);
  float2 bb = *(const float2*)&b2[lane * 2];
  float o0 = a0 * inv + bb.x, o1 = a1 * inv + bb.y;
  o0 = o0 > 0.f ? o0 : expm1f(o0);
  o1 = o1 > 0.f ? o1 : expm1f(o1);
  *(float2*)&out[(size_t)d * 128 + lane * 2] = make_float2(o0, o1);
}

// ---------------- pooling ----------------
#define NPB 512
__global__ __launch_bounds__(256) void pool_kernel(const float* __restrict__ y,
                                                   const int* __restrict__ batch,
                                                   float* __restrict__ psum) {
  int c = threadIdx.x & 127, sub = threadIdx.x >> 7;
  int n0 = blockIdx.x * NPB;
  int nend = n0 + NPB;
  if (nend > N_NODES) nend = N_NODES;
  int curg = -1;
  float acc = 0.f;
  for (int n = n0 + sub; n < nend; n += 2) {
    int gg = batch[n];
    if (gg != curg) {
      if (curg >= 0) atomicAdd(&psum[curg * 128 + c], acc);
      acc = 0.f;
      curg = gg;
    }
    acc += y[(size_t)n * 128 + c];
  }
  if (curg >= 0) atomicAdd(&psum[curg * 128 + c], acc);
}

__global__ __launch_bounds__(256) void gcnt_kernel(const int* __restrict__ batch,
                                                   float* __restrict__ cntg) {
  __shared__ int sh[N_GRAPHS];
  int t = threadIdx.x;
  if (t < N_GRAPHS) sh[t] = 0;
  __syncthreads();
  int n = blockIdx.x * 256 + t;
  if (n < N_NODES) atomicAdd(&sh[batch[n]], 1);
  __syncthreads();
  if (t < N_GRAPHS && sh[t]) atomicAdd(&cntg[t], (float)sh[t]);
}

__global__ __launch_bounds__(128) void fc_kernel(
    const float* __restrict__ psum, const float* __restrict__ cntg,
    const float* __restrict__ fcW, const float* __restrict__ fcb,
    float* __restrict__ out) {
  __shared__ float pr[128];
  int gb = blockIdx.x, c = threadIdx.x;
  float cnt = cntg[gb];
  cnt = cnt > 1.f ? cnt : 1.f;
  pr[c] = psum[gb * 128 + c] / cnt;
  __syncthreads();
  float s = fcb[c];
  #pragma unroll 8
  for (int k = 0; k < 128; k++) s += pr[k] * fcW[k * 128 + c];
  out[gb * 128 + c] = fmaxf(s, 0.f);
}

extern "C" void kernel_launch(void* const* d_in, const int* in_sizes, int n_in,
                              void* d_out, int out_size, void* d_ws,
                              size_t ws_size, hipStream_t stream) {
  const float* x      = (const float*)d_in[0];
  const int*   ei     = (const int*)d_in[1];
  const int*   batch  = (const int*)d_in[2];
  const float* W1     = (const float*)d_in[3];
  const float* a1_src = (const float*)d_in[4];
  const float* a1_dst = (const float*)d_in[5];
  const float* b1     = (const float*)d_in[6];
  const float* W2     = (const float*)d_in[7];
  const float* a2_src = (const float*)d_in[8];
  const float* a2_dst = (const float*)d_in[9];
  const float* b2     = (const float*)d_in[10];
  const float* fc_W   = (const float*)d_in[11];
  const float* fc_b   = (const float*)d_in[12];
  float* out = (float*)d_out;

  const int* srcp = ei;
  const int* dstp = ei + N_EDGES;
  const int NB = (N_NODES + 255) / 256;  // 196

  // ---- workspace layout ----
  float* x2   = (float*)d_ws;                 // [50000*256]
  float* y    = x2 + (size_t)N_NODES * 256;   // [50000*128]
  float* al1s = y + (size_t)N_NODES * 128;    // [200000]
  float* al1d = al1s + N_NODES * 4;
  float* al2s = al1d + N_NODES * 4;           // [50000]
  float* al2d = al2s + N_NODES;
  float* psum = al2d + N_NODES;               // [64*128]
  float* cntg = psum + N_GRAPHS * 128;        // [64]
  us* h1b  = (us*)(cntg + N_GRAPHS);          // [50000*256]
  us* h2b  = h1b + (size_t)N_NODES * 256;     // [50000*128]
  us* w1th = h2b + (size_t)N_NODES * 128;     // [256*128]
  us* w1tl = w1th + 256 * 128;
  us* w2th = w1tl + 256 * 128;                // [128*256]
  us* w2tl = w2th + 128 * 256;
  int* cnt    = (int*)(w2tl + 128 * 256);     // [50000]
  int* bsum   = cnt + N_NODES;                // [256]
  int* boff   = bsum + 256;                   // [256]
  int* itmp   = boff + 256;                   // [50000]
  int* rowst  = itmp + N_NODES;               // [50001]
  int* cursor = rowst + N_NODES + 8;          // [50000]
  int* csrc   = cursor + N_NODES;             // [800000]
  size_t needed = (size_t)((char*)(csrc + N_EDGES) - (char*)d_ws);
  if (ws_size < needed) return;

  hipMemsetAsync(cnt, 0, N_NODES * sizeof(int), stream);
  hipMemsetAsync(psum, 0, (N_GRAPHS * 128 + N_GRAPHS) * sizeof(float), stream);

  // CSR build
  count_kernel<<<(N_EDGES + 255) / 256, 256, 0, stream>>>(dstp, cnt);
  scan1_kernel<<<NB, 256, 0, stream>>>(cnt, itmp, bsum);
  scan2_kernel<<<1, 256, 0, stream>>>(bsum, boff, NB);
  scan3_kernel<<<NB, 256, 0, stream>>>(cnt, itmp, boff, rowst, cursor);
  scatter_kernel<<<(N_EDGES + 255) / 256, 256, 0, stream>>>(srcp, dstp, cursor, csrc);

  // weight prep
  convW_kernel<<<128, 256, 0, stream>>>(W1, w1th, w1tl, 128, 256);
  convW_kernel<<<128, 256, 0, stream>>>(W2, w2th, w2tl, 256, 128);

  // layer 1
  gemm_bf16x3<<<dim3(391, 2), 256, 0, stream>>>(x, w1th, w1tl, h1b, N_NODES, 256, 128);
  logits1_kernel<<<(N_NODES * 4 + 255) / 256, 256, 0, stream>>>(h1b, a1_src, a1_dst, al1s, al1d);
  agg1_kernel<<<(N_NODES + 3) / 4, 256, 0, stream>>>(h1b, al1s, al1d, rowst, csrc, b1, x2);

  // layer 2
  gemm_bf16x3<<<dim3(391, 1), 256, 0, stream>>>(x2, w2th, w2tl, h2b, N_NODES, 128, 256);
  logits2_kernel<<<(N_NODES + 255) / 256, 256, 0, stream>>>(h2b, a2_src, a2_dst, al2s, al2d);
  agg2_kernel<<<(N_NODES + 3) / 4, 256, 0, stream>>>(h2b, al2s, al2d, rowst, csrc, b2, y);

  // pool + fc
  pool_kernel<<<(N_NODES + NPB - 1) / NPB, 256, 0, stream>>>(y, batch, psum);
  gcnt_kernel<<<(N_NODES + 255) / 256, 256, 0, stream>>>(batch, cntg);
  fc_kernel<<<N_GRAPHS, 128, 0, stream>>>(psum, cntg, fc_W, fc_b, out);
}

// Round 3
// 337.043 us; speedup vs baseline: 1.9094x; 1.1960x over previous
//
#include <hip/hip_runtime.h>
#include <math.h>

#define N_NODES 50000
#define N_EDGES 800000
#define N_GRAPHS 64
#define NEG 0.2f

typedef unsigned short us;
typedef us us2 __attribute__((ext_vector_type(2)));
typedef us us4 __attribute__((ext_vector_type(4)));
typedef us us8 __attribute__((ext_vector_type(8)));
typedef short bf16x8 __attribute__((ext_vector_type(8)));
typedef float f32x4 __attribute__((ext_vector_type(4)));

__device__ __forceinline__ us bf16rn(float f) {
  unsigned int u = __float_as_uint(f);
  u += 0x7FFFu + ((u >> 16) & 1u);
  return (us)(u >> 16);
}
__device__ __forceinline__ float bf2f(us h) {
  return __uint_as_float(((unsigned int)h) << 16);
}

// ---------------- W conversion (both layers in one launch) ----------------
// W1[128,256] -> w1t hi/lo [256][128]; W2[256,128] -> w2t hi/lo [128][256]
__global__ __launch_bounds__(256) void convW_kernel(
    const float* __restrict__ W1, const float* __restrict__ W2,
    us* __restrict__ w1h, us* __restrict__ w1l,
    us* __restrict__ w2h, us* __restrict__ w2l) {
  int idx = blockIdx.x * 256 + threadIdx.x;
  const float* W; us *oh, *ol; int K, N, li;
  if (idx < 128 * 256) {
    W = W1; oh = w1h; ol = w1l; K = 128; N = 256; li = idx;
  } else if (idx < 2 * 128 * 256) {
    W = W2; oh = w2h; ol = w2l; K = 256; N = 128; li = idx - 128 * 256;
  } else return;
  int n = li / K, k = li - n * K;
  float f = W[(size_t)k * N + n];
  us h = bf16rn(f);
  oh[li] = h;
  ol[li] = bf16rn(f - bf2f(h));
}

// ---------------- MFMA GEMM, bf16x3 split precision ----------------
__global__ __launch_bounds__(256, 2) void gemm_bf16x3(
    const float* __restrict__ A, const us* __restrict__ Bth,
    const us* __restrict__ Btl, us* __restrict__ C, int M, int N, int K) {
  __shared__ us Ah[128][40];
  __shared__ us Al[128][40];
  __shared__ us Bh[128][40];
  __shared__ us Bl[128][40];
  int t = threadIdx.x;
  int m0 = blockIdx.x * 128;
  int n0 = blockIdx.y * 128;
  int w = t >> 6, l = t & 63;
  int wr = w >> 1, wc = w & 1;
  int l15 = l & 15, g = l >> 4;

  f32x4 acc[4][4] = {};

  for (int kb = 0; kb < K; kb += 32) {
    #pragma unroll
    for (int i = 0; i < 4; i++) {
      int slot = i * 256 + t;
      int row = slot >> 3, kq = slot & 7;
      float4 v = make_float4(0.f, 0.f, 0.f, 0.f);
      if (m0 + row < M) v = *(const float4*)&A[(size_t)(m0 + row) * K + kb + kq * 4];
      us h0 = bf16rn(v.x), h1 = bf16rn(v.y), h2 = bf16rn(v.z), h3 = bf16rn(v.w);
      us4 hv = {h0, h1, h2, h3};
      us4 lv = {bf16rn(v.x - bf2f(h0)), bf16rn(v.y - bf2f(h1)),
                bf16rn(v.z - bf2f(h2)), bf16rn(v.w - bf2f(h3))};
      *(us4*)&Ah[row][kq * 4] = hv;
      *(us4*)&Al[row][kq * 4] = lv;
    }
    #pragma unroll
    for (int i = 0; i < 2; i++) {
      int slot = i * 256 + t;
      int n = slot >> 2, kq = slot & 3;
      size_t gidx = (size_t)(n0 + n) * K + kb + kq * 8;
      *(us8*)&Bh[n][kq * 8] = *(const us8*)&Bth[gidx];
      *(us8*)&Bl[n][kq * 8] = *(const us8*)&Btl[gidx];
    }
    __syncthreads();

    bf16x8 af[4], al4[4], bf[4], bl4[4];
    #pragma unroll
    for (int i = 0; i < 4; i++) {
      af[i]  = *(const bf16x8*)&Ah[wr * 64 + i * 16 + l15][g * 8];
      al4[i] = *(const bf16x8*)&Al[wr * 64 + i * 16 + l15][g * 8];
      bf[i]  = *(const bf16x8*)&Bh[wc * 64 + i * 16 + l15][g * 8];
      bl4[i] = *(const bf16x8*)&Bl[wc * 64 + i * 16 + l15][g * 8];
    }
    #pragma unroll
    for (int i = 0; i < 4; i++)
      #pragma unroll
      for (int j = 0; j < 4; j++) {
        acc[i][j] = __builtin_amdgcn_mfma_f32_16x16x32_bf16(af[i], bf[j], acc[i][j], 0, 0, 0);
        acc[i][j] = __builtin_amdgcn_mfma_f32_16x16x32_bf16(af[i], bl4[j], acc[i][j], 0, 0, 0);
        acc[i][j] = __builtin_amdgcn_mfma_f32_16x16x32_bf16(al4[i], bf[j], acc[i][j], 0, 0, 0);
      }
    __syncthreads();
  }

  #pragma unroll
  for (int i = 0; i < 4; i++)
    #pragma unroll
    for (int j = 0; j < 4; j++)
      #pragma unroll
      for (int r = 0; r < 4; r++) {
        int row = m0 + wr * 64 + i * 16 + g * 4 + r;
        if (row < M) {
          int col = n0 + wc * 64 + j * 16 + l15;
          C[(size_t)row * N + col] = bf16rn(acc[i][j][r]);
        }
      }
}

// ---------------- logits layer 1 ----------------
__global__ __launch_bounds__(256) void logits1_kernel(
    const us* __restrict__ h1b, const float* __restrict__ a_src,
    const float* __restrict__ a_dst, float* __restrict__ al_s,
    float* __restrict__ al_d) {
  int idx = blockIdx.x * 256 + threadIdx.x;
  if (idx >= N_NODES * 4) return;
  int n = idx >> 2, h = idx & 3;
  const us* hp = &h1b[(size_t)n * 256 + h * 64];
  float ss = 0.f, sd = 0.f;
  #pragma unroll
  for (int i = 0; i < 8; i++) {
    us8 v = *(const us8*)&hp[i * 8];
    #pragma unroll
    for (int j = 0; j < 8; j++) {
      float f = bf2f(v[j]);
      ss += f * a_src[h * 64 + i * 8 + j];
      sd += f * a_dst[h * 64 + i * 8 + j];
    }
  }
  al_s[idx] = ss;
  al_d[idx] = sd;
}

// ---------------- logits layer 2 ----------------
__global__ __launch_bounds__(256) void logits2_kernel(
    const us* __restrict__ h2b, const float* __restrict__ a_src,
    const float* __restrict__ a_dst, float* __restrict__ al_s,
    float* __restrict__ al_d) {
  int n = blockIdx.x * 256 + threadIdx.x;
  if (n >= N_NODES) return;
  const us* hp = &h2b[(size_t)n * 128];
  float ss = 0.f, sd = 0.f;
  #pragma unroll
  for (int i = 0; i < 16; i++) {
    us8 v = *(const us8*)&hp[i * 8];
    #pragma unroll
    for (int j = 0; j < 8; j++) {
      float f = bf2f(v[j]);
      ss += f * a_src[i * 8 + j];
      sd += f * a_dst[i * 8 + j];
    }
  }
  al_s[n] = ss;
  al_d[n] = sd;
}

// ---------------- CSR build ----------------
__global__ __launch_bounds__(256) void count_kernel(const int* __restrict__ dst,
                                                    int* __restrict__ cnt) {
  int e = blockIdx.x * 256 + threadIdx.x;
  if (e < N_EDGES) atomicAdd(&cnt[dst[e]], 1);
}

__global__ __launch_bounds__(256) void scan1_kernel(const int* __restrict__ cnt,
                                                    int* __restrict__ itmp,
                                                    int* __restrict__ bsum) {
  int i = blockIdx.x * 256 + threadIdx.x;
  int v = (i < N_NODES) ? cnt[i] : 0;
  int lane = threadIdx.x & 63, w = threadIdx.x >> 6;
  int s = v;
  #pragma unroll
  for (int off = 1; off < 64; off <<= 1) {
    int tv = __shfl_up(s, off);
    if (lane >= off) s += tv;
  }
  __shared__ int wsum[4];
  if (lane == 63) wsum[w] = s;
  __syncthreads();
  int add = 0;
  for (int p = 0; p < w; p++) add += wsum[p];
  s += add;
  if (i < N_NODES) itmp[i] = s;
  if (threadIdx.x == 255) bsum[blockIdx.x] = s;
}

__global__ __launch_bounds__(256) void scan2_kernel(const int* __restrict__ bsum,
                                                    int* __restrict__ boff,
                                                    int nb) {
  int t = threadIdx.x;
  int v = (t < nb) ? bsum[t] : 0;
  int lane = t & 63, w = t >> 6;
  int s = v;
  #pragma unroll
  for (int off = 1; off < 64; off <<= 1) {
    int tv = __shfl_up(s, off);
    if (lane >= off) s += tv;
  }
  __shared__ int wsum[4];
  if (lane == 63) wsum[w] = s;
  __syncthreads();
  int add = 0;
  for (int p = 0; p < w; p++) add += wsum[p];
  s += add;
  if (t < nb) boff[t] = s - v;
}

__global__ __launch_bounds__(256) void scan3_kernel(const int* __restrict__ cnt,
                                                    const int* __restrict__ itmp,
                                                    const int* __restrict__ boff,
                                                    int* __restrict__ rowst,
                                                    int* __restrict__ cursor) {
  int i = blockIdx.x * 256 + threadIdx.x;
  if (i < N_NODES) {
    int excl = itmp[i] - cnt[i] + boff[i >> 8];
    rowst[i] = excl;
    cursor[i] = excl;
  }
  if (i == 0) rowst[N_NODES] = N_EDGES;
}

__global__ __launch_bounds__(256) void scatter_kernel(
    const int* __restrict__ src, const int* __restrict__ dst,
    int* __restrict__ cursor, int* __restrict__ csr_src) {
  int e = blockIdx.x * 256 + threadIdx.x;
  if (e < N_EDGES) {
    int p = atomicAdd(&cursor[dst[e]], 1);
    csr_src[p] = src[e];
  }
}

// ---------------- layer-1 aggregation: 2 half-waves per dst node ----------------
__device__ __forceinline__ void agg1_edge(int s, int head, int c0,
                                          float ald,
                                          const float* __restrict__ al_s,
                                          const us* __restrict__ h1b,
                                          float& wsum, float& a0, float& a1) {
  float al = al_s[s * 4 + head];
  us2 hv = *(const us2*)&h1b[(size_t)s * 256 + c0];
  float e = al + ald;
  e = e > 0.f ? e : NEG * e;
  float wgt = __expf(e);
  wsum += wgt;
  a0 += wgt * bf2f(hv[0]);
  a1 += wgt * bf2f(hv[1]);
}

__global__ __launch_bounds__(256) void agg1_kernel(
    const us* __restrict__ h1b, const float* __restrict__ al_s,
    const float* __restrict__ al_d, const int* __restrict__ rowst,
    const int* __restrict__ csrc, const float* __restrict__ b1,
    float* __restrict__ out) {
  int wid = (blockIdx.x * 256 + threadIdx.x) >> 6;  // global wave id
  int lane = threadIdx.x & 63;
  int d = wid >> 1, hf = wid & 1;
  if (d >= N_NODES) return;
  int c0 = hf * 128 + lane * 2;      // 2 channels per lane
  int head = c0 >> 6;
  float ald = al_d[d * 4 + head];
  float wsum = 0.f, a0 = 0.f, a1 = 0.f;
  int beg = rowst[d], end = rowst[d + 1];
  agg1_edge(d, head, c0, ald, al_s, h1b, wsum, a0, a1);  // self-loop
  int j = beg;
  for (; j + 3 < end; j += 4) {
    int s0 = csrc[j], s1 = csrc[j + 1], s2 = csrc[j + 2], s3 = csrc[j + 3];
    agg1_edge(s0, head, c0, ald, al_s, h1b, wsum, a0, a1);
    agg1_edge(s1, head, c0, ald, al_s, h1b, wsum, a0, a1);
    agg1_edge(s2, head, c0, ald, al_s, h1b, wsum, a0, a1);
    agg1_edge(s3, head, c0, ald, al_s, h1b, wsum, a0, a1);
  }
  for (; j < end; ++j) agg1_edge(csrc[j], head, c0, ald, al_s, h1b, wsum, a0, a1);
  float inv = 1.f / (wsum + 1e-16f);
  float2 bb = *(const float2*)&b1[c0];
  float o0 = a0 * inv + bb.x, o1 = a1 * inv + bb.y;
  o0 = o0 > 0.f ? o0 : expm1f(o0);
  o1 = o1 > 0.f ? o1 : expm1f(o1);
  *(float2*)&out[(size_t)d * 256 + c0] = make_float2(o0, o1);
}

// ---------------- layer-2 aggregation: one wave per dst node ----------------
__device__ __forceinline__ void agg2_edge(int s, int lane, float ald,
                                          const float* __restrict__ al_s,
                                          const us* __restrict__ h2b,
                                          float& wsum, float& a0, float& a1) {
  float e = al_s[s] + ald;
  e = e > 0.f ? e : NEG * e;
  float wgt = __expf(e);
  wsum += wgt;
  us2 hv = *(const us2*)&h2b[(size_t)s * 128 + lane * 2];
  a0 += wgt * bf2f(hv[0]);
  a1 += wgt * bf2f(hv[1]);
}

__global__ __launch_bounds__(256) void agg2_kernel(
    const us* __restrict__ h2b, const float* __restrict__ al_s,
    const float* __restrict__ al_d, const int* __restrict__ rowst,
    const int* __restrict__ csrc, const float* __restrict__ b2,
    float* __restrict__ out) {
  int d = (blockIdx.x * 256 + threadIdx.x) >> 6;
  int lane = threadIdx.x & 63;
  if (d >= N_NODES) return;
  float ald = al_d[d];
  float wsum = 0.f, a0 = 0.f, a1 = 0.f;
  int beg = rowst[d], end = rowst[d + 1];
  agg2_edge(d, lane, ald, al_s, h2b, wsum, a0, a1);  // self-loop
  int j = beg;
  for (; j + 3 < end; j += 4) {
    int s0 = csrc[j], s1 = csrc[j + 1], s2 = csrc[j + 2], s3 = csrc[j + 3];
    agg2_edge(s0, lane, ald, al_s, h2b, wsum, a0, a1);
    agg2_edge(s1, lane, ald, al_s, h2b, wsum, a0, a1);
    agg2_edge(s2, lane, ald, al_s, h2b, wsum, a0, a1);
    agg2_edge(s3, lane, ald, al_s, h2b, wsum, a0, a1);
  }
  for (; j < end; ++j) agg2_edge(csrc[j], lane, ald, al_s, h2b, wsum, a0, a1);
  float inv = 1.f / (wsum + 1e-16f);
  float2 bb = *(const float2*)&b2[lane * 2];
  float o0 = a0 * inv + bb.x, o1 = a1 * inv + bb.y;
  o0 = o0 > 0.f ? o0 : expm1f(o0);
  o1 = o1 > 0.f ? o1 : expm1f(o1);
  *(float2*)&out[(size_t)d * 128 + lane * 2] = make_float2(o0, o1);
}

// ---------------- pooling: 391 blocks, 8 subs x 32 float4-lanes ----------------
#define PNPB 128
__global__ __launch_bounds__(256) void pool_kernel(const float* __restrict__ y,
                                                   const int* __restrict__ batch,
                                                   float* __restrict__ psum) {
  int t = threadIdx.x;
  int lane32 = t & 31;   // float4 channel group
  int sub = t >> 5;      // 0..7
  int base = blockIdx.x * PNPB + sub * (PNPB / 8);
  int nend = base + PNPB / 8;
  if (nend > N_NODES) nend = N_NODES;
  float4 acc = make_float4(0.f, 0.f, 0.f, 0.f);
  int curg = -1;
  for (int n = base; n < nend; ++n) {
    int g = batch[n];
    if (g != curg) {
      if (curg >= 0) {
        float* p = &psum[curg * 128 + lane32 * 4];
        atomicAdd(p + 0, acc.x); atomicAdd(p + 1, acc.y);
        atomicAdd(p + 2, acc.z); atomicAdd(p + 3, acc.w);
      }
      acc = make_float4(0.f, 0.f, 0.f, 0.f);
      curg = g;
    }
    float4 v = *(const float4*)&y[(size_t)n * 128 + lane32 * 4];
    acc.x += v.x; acc.y += v.y; acc.z += v.z; acc.w += v.w;
  }
  if (curg >= 0) {
    float* p = &psum[curg * 128 + lane32 * 4];
    atomicAdd(p + 0, acc.x); atomicAdd(p + 1, acc.y);
    atomicAdd(p + 2, acc.z); atomicAdd(p + 3, acc.w);
  }
}

// ---------------- mean + FC + ReLU (count via binary search on sorted batch) ----------------
__global__ __launch_bounds__(128) void fc_kernel(
    const float* __restrict__ psum, const int* __restrict__ batch,
    const float* __restrict__ fcW, const float* __restrict__ fcb,
    float* __restrict__ out) {
  __shared__ float pr[128];
  __shared__ int bounds[2];
  int g = blockIdx.x, c = threadIdx.x;
  if (c < 2) {
    int target = g + c;
    int lo = 0, hi = N_NODES;
    while (lo < hi) {
      int mid = (lo + hi) >> 1;
      if (batch[mid] < target) lo = mid + 1; else hi = mid;
    }
    bounds[c] = lo;
  }
  __syncthreads();
  float cnt = (float)(bounds[1] - bounds[0]);
  cnt = cnt > 1.f ? cnt : 1.f;
  pr[c] = psum[g * 128 + c] / cnt;
  __syncthreads();
  float s = fcb[c];
  #pragma unroll 8
  for (int k = 0; k < 128; k++) s += pr[k] * fcW[k * 128 + c];
  out[g * 128 + c] = fmaxf(s, 0.f);
}

extern "C" void kernel_launch(void* const* d_in, const int* in_sizes, int n_in,
                              void* d_out, int out_size, void* d_ws,
                              size_t ws_size, hipStream_t stream) {
  const float* x      = (const float*)d_in[0];
  const int*   ei     = (const int*)d_in[1];
  const int*   batch  = (const int*)d_in[2];
  const float* W1     = (const float*)d_in[3];
  const float* a1_src = (const float*)d_in[4];
  const float* a1_dst = (const float*)d_in[5];
  const float* b1     = (const float*)d_in[6];
  const float* W2     = (const float*)d_in[7];
  const float* a2_src = (const float*)d_in[8];
  const float* a2_dst = (const float*)d_in[9];
  const float* b2     = (const float*)d_in[10];
  const float* fc_W   = (const float*)d_in[11];
  const float* fc_b   = (const float*)d_in[12];
  float* out = (float*)d_out;

  const int* srcp = ei;
  const int* dstp = ei + N_EDGES;
  const int NB = (N_NODES + 255) / 256;  // 196

  // ---- workspace layout ----
  float* x2   = (float*)d_ws;                 // [50000*256]
  float* y    = x2 + (size_t)N_NODES * 256;   // [50000*128]
  float* al1s = y + (size_t)N_NODES * 128;    // [200000]
  float* al1d = al1s + N_NODES * 4;
  float* al2s = al1d + N_NODES * 4;           // [50000]
  float* al2d = al2s + N_NODES;
  float* psum = al2d + N_NODES;               // [64*128]
  us* h1b  = (us*)(psum + N_GRAPHS * 128);    // [50000*256]
  us* h2b  = h1b + (size_t)N_NODES * 256;     // [50000*128]
  us* w1th = h2b + (size_t)N_NODES * 128;     // [256*128]
  us* w1tl = w1th + 256 * 128;
  us* w2th = w1tl + 256 * 128;                // [128*256]
  us* w2tl = w2th + 128 * 256;
  int* cnt    = (int*)(w2tl + 128 * 256);     // [50000]
  int* bsum   = cnt + N_NODES;                // [256]
  int* boff   = bsum + 256;                   // [256]
  int* itmp   = boff + 256;                   // [50000]
  int* rowst  = itmp + N_NODES;               // [50001]
  int* cursor = rowst + N_NODES + 8;          // [50000]
  int* csrc   = cursor + N_NODES;             // [800000]
  size_t needed = (size_t)((char*)(csrc + N_EDGES) - (char*)d_ws);
  if (ws_size < needed) return;

  hipMemsetAsync(cnt, 0, N_NODES * sizeof(int), stream);
  hipMemsetAsync(psum, 0, N_GRAPHS * 128 * sizeof(float), stream);

  // CSR build
  count_kernel<<<(N_EDGES + 255) / 256, 256, 0, stream>>>(dstp, cnt);
  scan1_kernel<<<NB, 256, 0, stream>>>(cnt, itmp, bsum);
  scan2_kernel<<<1, 256, 0, stream>>>(bsum, boff, NB);
  scan3_kernel<<<NB, 256, 0, stream>>>(cnt, itmp, boff, rowst, cursor);
  scatter_kernel<<<(N_EDGES + 255) / 256, 256, 0, stream>>>(srcp, dstp, cursor, csrc);

  // weight prep (single launch)
  convW_kernel<<<(2 * 128 * 256 + 255) / 256, 256, 0, stream>>>(
      W1, W2, w1th, w1tl, w2th, w2tl);

  // layer 1
  gemm_bf16x3<<<dim3(391, 2), 256, 0, stream>>>(x, w1th, w1tl, h1b, N_NODES, 256, 128);
  logits1_kernel<<<(N_NODES * 4 + 255) / 256, 256, 0, stream>>>(h1b, a1_src, a1_dst, al1s, al1d);
  agg1_kernel<<<(N_NODES * 2 * 64 + 255) / 256, 256, 0, stream>>>(h1b, al1s, al1d, rowst, csrc, b1, x2);

  // layer 2
  gemm_bf16x3<<<dim3(391, 1), 256, 0, stream>>>(x2, w2th, w2tl, h2b, N_NODES, 128, 256);
  logits2_kernel<<<(N_NODES + 255) / 256, 256, 0, stream>>>(h2b, a2_src, a2_dst, al2s, al2d);
  agg2_kernel<<<(N_NODES + 3) / 4, 256, 0, stream>>>(h2b, al2s, al2d, rowst, csrc, b2, y);

  // pool + fc
  pool_kernel<<<(N_NODES + PNPB - 1) / PNPB, 256, 0, stream>>>(y, batch, psum);
  fc_kernel<<<N_GRAPHS, 128, 0, stream>>>(psum, batch, fc_W, fc_b, out);
}